// Round 2
// baseline (634.549 us; speedup 1.0000x reference)
//
#include <hip/hip_runtime.h>
#include <hip/hip_bf16.h>

#define T_TOK 4096
#define D_DIM 1024
#define E_NUM 8
#define F_DIM 4096
#define NPAIR 8192

#define BM 128
#define BN 128
#define BK 64
#define KSPLIT 4

typedef float f32x4 __attribute__((ext_vector_type(4)));
typedef __bf16 bf16x8 __attribute__((ext_vector_type(8)));
typedef unsigned short u16x8 __attribute__((ext_vector_type(8)));

__device__ __forceinline__ unsigned short f2bf(float f) {
    unsigned int u = __float_as_uint(f);
    u += 0x7fffu + ((u >> 16) & 1u);
    return (unsigned short)(u >> 16);
}

typedef const __attribute__((address_space(1))) void GV;
typedef __attribute__((address_space(3))) void LV;

__device__ __forceinline__ void load_lds16(const void* g, void* l) {
    __builtin_amdgcn_global_load_lds((GV*)g, (LV*)l, 16, 0, 0);
}

// ---------------- Router: one wave per token ----------------
__global__ __launch_bounds__(256) void router_kernel(
    const float* __restrict__ x, const float* __restrict__ noise,
    const float* __restrict__ Wg, const float* __restrict__ bg,
    const float* __restrict__ Wn, const float* __restrict__ bn,
    float* __restrict__ out_noisy, float* __restrict__ out_gate,
    int* __restrict__ tk_idx, float* __restrict__ tk_w)
{
    int lane = threadIdx.x & 63;
    int t = blockIdx.x * 4 + (threadIdx.x >> 6);
    const float* xr = x + (size_t)t * D_DIM;

    float ag[E_NUM] = {}, an[E_NUM] = {};
    for (int it = 0; it < D_DIM / 64; ++it) {
        int d = it * 64 + lane;
        float xv = xr[d];
        float4 g0 = *(const float4*)(Wg + (size_t)d * E_NUM);
        float4 g1 = *(const float4*)(Wg + (size_t)d * E_NUM + 4);
        float4 m0 = *(const float4*)(Wn + (size_t)d * E_NUM);
        float4 m1 = *(const float4*)(Wn + (size_t)d * E_NUM + 4);
        ag[0] += xv * g0.x; ag[1] += xv * g0.y; ag[2] += xv * g0.z; ag[3] += xv * g0.w;
        ag[4] += xv * g1.x; ag[5] += xv * g1.y; ag[6] += xv * g1.z; ag[7] += xv * g1.w;
        an[0] += xv * m0.x; an[1] += xv * m0.y; an[2] += xv * m0.z; an[3] += xv * m0.w;
        an[4] += xv * m1.x; an[5] += xv * m1.y; an[6] += xv * m1.z; an[7] += xv * m1.w;
    }
    #pragma unroll
    for (int off = 32; off > 0; off >>= 1) {
        #pragma unroll
        for (int e = 0; e < E_NUM; ++e) {
            ag[e] += __shfl_xor(ag[e], off);
            an[e] += __shfl_xor(an[e], off);
        }
    }
    if (lane == 0) {
        float nz[E_NUM];
        #pragma unroll
        for (int e = 0; e < E_NUM; ++e) {
            float g = ag[e] + bg[e];
            float nn = an[e] + bn[e];
            float sp = fmaxf(nn, 0.f) + log1pf(expf(-fabsf(nn)));
            float z = g + noise[(size_t)t * E_NUM + e] * sp;
            out_gate[(size_t)t * E_NUM + e] = g;
            out_noisy[(size_t)t * E_NUM + e] = z;
            nz[e] = z;
        }
        int e0 = 0;
        #pragma unroll
        for (int e = 1; e < E_NUM; ++e) if (nz[e] > nz[e0]) e0 = e;
        int e1 = (e0 == 0) ? 1 : 0;
        #pragma unroll
        for (int e = 0; e < E_NUM; ++e) if (e != e0 && nz[e] > nz[e1]) e1 = e;
        float b = expf(nz[e1] - nz[e0]);  // <= 1
        float w0 = 1.f / (1.f + b);
        float w1 = b / (1.f + b);
        tk_idx[t * 2] = e0;  tk_idx[t * 2 + 1] = e1;
        tk_w[t * 2] = w0;    tk_w[t * 2 + 1] = w1;
    }
}

// ---------------- Deterministic group-by-expert (1 block) ----------------
__global__ __launch_bounds__(256) void scan_scatter_kernel(
    const int* __restrict__ tk_idx,
    int* __restrict__ perm, int* __restrict__ meta)
{
    __shared__ int cnt[256][E_NUM];
    __shared__ int soff[E_NUM];
    int tid = threadIdx.x;
    const int PPT = NPAIR / 256;   // 32 pairs per thread
    int p0 = tid * PPT;

    int c[E_NUM] = {};
    for (int i = 0; i < PPT; ++i) c[tk_idx[p0 + i]]++;
    #pragma unroll
    for (int e = 0; e < E_NUM; ++e) cnt[tid][e] = c[e];
    __syncthreads();

    if (tid < E_NUM) {
        int s = 0;
        for (int j = 0; j < 256; ++j) { int v = cnt[j][tid]; cnt[j][tid] = s; s += v; }
        soff[tid] = s;
    }
    __syncthreads();

    if (tid == 0) {
        int off = 0, nt = 0;
        for (int e = 0; e < E_NUM; ++e) {
            int ce = soff[e];
            meta[1 + e] = off;
            meta[9 + e] = ce;
            for (int j = 0; j < ce; j += BM) {
                meta[32 + nt]  = e;
                meta[160 + nt] = off + j;
                meta[288 + nt] = off + ce;
                nt++;
            }
            off += ce;
        }
        meta[0] = nt;
    }
    __syncthreads();
    if (tid < E_NUM) soff[tid] = meta[1 + tid];
    __syncthreads();

    int pos[E_NUM];
    #pragma unroll
    for (int e = 0; e < E_NUM; ++e) pos[e] = soff[e] + cnt[tid][e];
    for (int i = 0; i < PPT; ++i) {
        int e = tk_idx[p0 + i];
        perm[pos[e]++] = p0 + i;
    }
}

// ---------------- x fp32 -> bf16 ----------------
__global__ __launch_bounds__(256) void convert_x_kernel(
    const float* __restrict__ x, unsigned short* __restrict__ xb)
{
    size_t i = ((size_t)blockIdx.x * 256 + threadIdx.x) * 8;
    float4 a = *(const float4*)(x + i);
    float4 b = *(const float4*)(x + i + 4);
    u16x8 o;
    o[0] = f2bf(a.x); o[1] = f2bf(a.y); o[2] = f2bf(a.z); o[3] = f2bf(a.w);
    o[4] = f2bf(b.x); o[5] = f2bf(b.y); o[6] = f2bf(b.z); o[7] = f2bf(b.w);
    *(u16x8*)(xb + i) = o;
}

// ---------------- W [E][R][C] f32 -> WT [E][C][R] bf16 ----------------
__global__ __launch_bounds__(256) void transpose_kernel(
    const float* __restrict__ W, unsigned short* __restrict__ WT, int R, int C)
{
    __shared__ float tile[32][33];
    int e = blockIdx.z;
    int c0 = blockIdx.x * 32, r0 = blockIdx.y * 32;
    int tx = threadIdx.x & 31, ty = threadIdx.x >> 5;  // ty: 0..7
    const float* src = W + (size_t)e * R * C;
    #pragma unroll
    for (int i = 0; i < 4; ++i)
        tile[ty + 8 * i][tx] = src[(size_t)(r0 + ty + 8 * i) * C + c0 + tx];
    __syncthreads();
    unsigned short* dst = WT + (size_t)e * C * R;
    #pragma unroll
    for (int i = 0; i < 4; ++i)
        dst[(size_t)(c0 + ty + 8 * i) * R + r0 + tx] = f2bf(tile[tx][ty + 8 * i]);
}

// ---------------- FC1: h = gelu(x @ W1 + b1), grouped by expert ----------------
__global__ __launch_bounds__(256) void fc1_kernel(
    const unsigned short* __restrict__ xb,    // [T][D] bf16
    const unsigned short* __restrict__ W1T,   // [E][F][D] bf16
    const float* __restrict__ b1,             // [E][F]
    const int* __restrict__ perm,
    const int* __restrict__ meta,
    unsigned short* __restrict__ h)           // [NPAIR][F] bf16
{
    int tile = blockIdx.x;
    if (tile >= meta[0]) return;
    int e    = meta[32 + tile];
    int rs   = meta[160 + tile];
    int rend = meta[288 + tile];
    int n0 = blockIdx.y * BN;

    __shared__ unsigned short As[BM][BK];   // [row][k]
    __shared__ unsigned short Bs[BN][BK];   // [n=f][k=d]  (B^T)

    int tid = threadIdx.x, lane = tid & 63, wv = tid >> 6;
    int wm = (wv >> 1) * 64, wn = (wv & 1) * 64;

    // per-lane gathered global A sources; LDS dest stays linear per wave
    const unsigned short* asrc[4];
    #pragma unroll
    for (int i = 0; i < 4; ++i) {
        int q = tid + i * 256;
        int r = q >> 3, c = q & 7;
        int pos = rs + r; if (pos >= NPAIR) pos = NPAIR - 1;
        int t = perm[pos] >> 1;
        asrc[i] = xb + (size_t)t * D_DIM + c * 8;
    }
    unsigned short* Asf = &As[0][0];
    const unsigned short* bbase = W1T + ((size_t)e * F_DIM + n0 + wv * 32 + (lane >> 3)) * D_DIM
                                + (lane & 7) * 8;

    f32x4 acc[4][4] = {};

    for (int k0 = 0; k0 < D_DIM; k0 += BK) {
        __syncthreads();
        #pragma unroll
        for (int i = 0; i < 4; ++i)
            load_lds16(asrc[i] + k0, Asf + ((size_t)wv * 64 + i * 256) * 8);
        #pragma unroll
        for (int j = 0; j < 4; ++j)
            load_lds16(bbase + (size_t)j * 8 * D_DIM + k0, &Bs[wv * 32 + j * 8][0]);
        __syncthreads();
        #pragma unroll
        for (int kk = 0; kk < BK; kk += 32) {
            bf16x8 af[4], bf[4];
            #pragma unroll
            for (int m = 0; m < 4; ++m)
                af[m] = *(const bf16x8*)&As[wm + m * 16 + (lane & 15)][kk + (lane >> 4) * 8];
            #pragma unroll
            for (int n = 0; n < 4; ++n)
                bf[n] = *(const bf16x8*)&Bs[wn + n * 16 + (lane & 15)][kk + (lane >> 4) * 8];
            #pragma unroll
            for (int m = 0; m < 4; ++m)
                #pragma unroll
                for (int n = 0; n < 4; ++n)
                    acc[m][n] = __builtin_amdgcn_mfma_f32_16x16x32_bf16(af[m], bf[n], acc[m][n], 0, 0, 0);
        }
    }

    #pragma unroll
    for (int m = 0; m < 4; ++m) {
        #pragma unroll
        for (int j = 0; j < 4; ++j) {
            int r = wm + m * 16 + (lane >> 4) * 4 + j;
            int pos = rs + r;
            if (pos >= rend) continue;
            #pragma unroll
            for (int n = 0; n < 4; ++n) {
                int col = n0 + wn + n * 16 + (lane & 15);
                float v = acc[m][n][j] + b1[e * F_DIM + col];
                v = 0.5f * v * (1.f + erff(v * 0.70710678118654752f));  // exact GELU
                h[(size_t)pos * F_DIM + col] = f2bf(v);
            }
        }
    }
}

// ---------------- FC2: out += w * (h @ W2 + b2), grouped, split-K ----------------
__global__ __launch_bounds__(256) void fc2_kernel(
    const unsigned short* __restrict__ h,     // [NPAIR][F] bf16
    const unsigned short* __restrict__ W2T,   // [E][D][F] bf16
    const float* __restrict__ b2,             // [E][D]
    const int* __restrict__ perm,
    const float* __restrict__ tk_w,
    const int* __restrict__ meta,
    float* __restrict__ out)                  // [T][D] fp32 (zeroed)
{
    int tile = blockIdx.x;
    if (tile >= meta[0]) return;
    int e    = meta[32 + tile];
    int rs   = meta[160 + tile];
    int rend = meta[288 + tile];
    int n0 = blockIdx.y * BN;                  // d block
    int ks   = blockIdx.z;                     // K split
    int kbeg = ks * (F_DIM / KSPLIT);
    int kend = kbeg + (F_DIM / KSPLIT);

    __shared__ unsigned short As[BM][BK];   // [row][k=f]
    __shared__ unsigned short Bs[BN][BK];   // [n=d][k=f]

    int tid = threadIdx.x, lane = tid & 63, wv = tid >> 6;
    int wm = (wv >> 1) * 64, wn = (wv & 1) * 64;

    // per-lane gathered A sources
    const unsigned short* asrc[4];
    #pragma unroll
    for (int i = 0; i < 4; ++i) {
        int q = tid + i * 256;
        int r = q >> 3, c = q & 7;
        int pos = rs + r; if (pos >= NPAIR) pos = NPAIR - 1;
        asrc[i] = h + (size_t)pos * F_DIM + c * 8;
    }
    unsigned short* Asf = &As[0][0];
    const unsigned short* bbase = W2T + ((size_t)e * D_DIM + n0 + wv * 32 + (lane >> 3)) * F_DIM
                                + (lane & 7) * 8;

    f32x4 acc[4][4] = {};

    for (int k0 = kbeg; k0 < kend; k0 += BK) {
        __syncthreads();
        #pragma unroll
        for (int i = 0; i < 4; ++i)
            load_lds16(asrc[i] + k0, Asf + ((size_t)wv * 64 + i * 256) * 8);
        #pragma unroll
        for (int j = 0; j < 4; ++j)
            load_lds16(bbase + (size_t)j * 8 * F_DIM + k0, &Bs[wv * 32 + j * 8][0]);
        __syncthreads();
        #pragma unroll
        for (int kk = 0; kk < BK; kk += 32) {
            bf16x8 af[4], bf[4];
            #pragma unroll
            for (int m = 0; m < 4; ++m)
                af[m] = *(const bf16x8*)&As[wm + m * 16 + (lane & 15)][kk + (lane >> 4) * 8];
            #pragma unroll
            for (int n = 0; n < 4; ++n)
                bf[n] = *(const bf16x8*)&Bs[wn + n * 16 + (lane & 15)][kk + (lane >> 4) * 8];
            #pragma unroll
            for (int m = 0; m < 4; ++m)
                #pragma unroll
                for (int n = 0; n < 4; ++n)
                    acc[m][n] = __builtin_amdgcn_mfma_f32_16x16x32_bf16(af[m], bf[n], acc[m][n], 0, 0, 0);
        }
    }

    #pragma unroll
    for (int m = 0; m < 4; ++m) {
        #pragma unroll
        for (int j = 0; j < 4; ++j) {
            int r = wm + m * 16 + (lane >> 4) * 4 + j;
            int pos = rs + r;
            if (pos >= rend) continue;
            int pr = perm[pos];
            int t = pr >> 1;
            float w = tk_w[pr];
            #pragma unroll
            for (int n = 0; n < 4; ++n) {
                int col = n0 + wn + n * 16 + (lane & 15);
                float base = (ks == 0) ? b2[e * D_DIM + col] : 0.f;
                float v = (acc[m][n][j] + base) * w;
                atomicAdd(&out[(size_t)t * D_DIM + col], v);
            }
        }
    }
}

extern "C" void kernel_launch(void* const* d_in, const int* in_sizes, int n_in,
                              void* d_out, int out_size, void* d_ws, size_t ws_size,
                              hipStream_t stream)
{
    const float* x     = (const float*)d_in[0];
    const float* noise = (const float*)d_in[1];
    const float* Wg    = (const float*)d_in[2];
    const float* bg    = (const float*)d_in[3];
    const float* Wn    = (const float*)d_in[4];
    const float* bn    = (const float*)d_in[5];
    const float* W1    = (const float*)d_in[6];
    const float* b1    = (const float*)d_in[7];
    const float* W2    = (const float*)d_in[8];
    const float* b2    = (const float*)d_in[9];

    float* out       = (float*)d_out;
    float* out_noisy = out + (size_t)T_TOK * D_DIM;
    float* out_gate  = out_noisy + (size_t)T_TOK * E_NUM;

    char* ws = (char*)d_ws;
    int*   tk_idx = (int*)ws;                    // 8192 ints
    float* tk_w   = (float*)(ws + 32768);        // 8192 floats
    int*   perm   = (int*)(ws + 65536);          // 8192 ints
    int*   meta   = (int*)(ws + 98304);          // 512 ints
    size_t off = 131072;
    unsigned short* xb   = (unsigned short*)(ws + off); off += (size_t)T_TOK * D_DIM * 2;
    unsigned short* W1T  = (unsigned short*)(ws + off); off += (size_t)E_NUM * F_DIM * D_DIM * 2;
    unsigned short* W2T  = (unsigned short*)(ws + off); off += (size_t)E_NUM * D_DIM * F_DIM * 2;
    unsigned short* hbuf = (unsigned short*)(ws + off); off += (size_t)NPAIR * F_DIM * 2;

    hipMemsetAsync(d_out, 0, (size_t)out_size * sizeof(float), stream);

    router_kernel<<<T_TOK / 4, 256, 0, stream>>>(x, noise, Wg, bg, Wn, bn,
                                                 out_noisy, out_gate, tk_idx, tk_w);
    scan_scatter_kernel<<<1, 256, 0, stream>>>(tk_idx, perm, meta);
    convert_x_kernel<<<(T_TOK * D_DIM) / (256 * 8), 256, 0, stream>>>(x, xb);
    transpose_kernel<<<dim3(F_DIM / 32, D_DIM / 32, E_NUM), 256, 0, stream>>>(W1, W1T, D_DIM, F_DIM);
    transpose_kernel<<<dim3(D_DIM / 32, F_DIM / 32, E_NUM), 256, 0, stream>>>(W2, W2T, F_DIM, D_DIM);

    fc1_kernel<<<dim3(71, F_DIM / BN), 256, 0, stream>>>(xb, W1T, b1, perm, meta, hbuf);
    fc2_kernel<<<dim3(71, D_DIM / BN, KSPLIT), 256, 0, stream>>>(hbuf, W2T, b2, perm, tk_w, meta, out);
}

// Round 3
// 505.910 us; speedup vs baseline: 1.2543x; 1.2543x over previous
//
#include <hip/hip_runtime.h>
#include <hip/hip_bf16.h>

#define T_TOK 4096
#define D_DIM 1024
#define E_NUM 8
#define F_DIM 4096
#define NPAIR 8192

#define BM 128
#define BN 128
#define BK 64

typedef float f32x4 __attribute__((ext_vector_type(4)));
typedef __bf16 bf16x8 __attribute__((ext_vector_type(8)));
typedef unsigned short u16x8 __attribute__((ext_vector_type(8)));

__device__ __forceinline__ unsigned short f2bf(float f) {
    unsigned int u = __float_as_uint(f);
    u += 0x7fffu + ((u >> 16) & 1u);
    return (unsigned short)(u >> 16);
}

typedef const __attribute__((address_space(1))) void GV;
typedef __attribute__((address_space(3))) void LV;

__device__ __forceinline__ void load_lds16(const void* g, void* l) {
    __builtin_amdgcn_global_load_lds((GV*)g, (LV*)l, 16, 0, 0);
}

// Swizzled LDS fragment read: logical (row, colShort cs) lives at
// byte = row*128 + ((cs*2) ^ ((row&7)<<4)).  Writer side: gload_lds writes
// linearly; the per-lane GLOBAL source column carries the inverse permutation.
__device__ __forceinline__ bf16x8 lds_frag(const unsigned short* S, int row, int cs) {
    int byte = row * (BK * 2) + ((cs * 2) ^ ((row & 7) << 4));
    return *(const bf16x8*)((const char*)S + byte);
}

// ---------------- Router: one wave per token ----------------
__global__ __launch_bounds__(256) void router_kernel(
    const float* __restrict__ x, const float* __restrict__ noise,
    const float* __restrict__ Wg, const float* __restrict__ bg,
    const float* __restrict__ Wn, const float* __restrict__ bn,
    float* __restrict__ out_noisy, float* __restrict__ out_gate,
    int* __restrict__ tk_idx, float* __restrict__ tk_w)
{
    int lane = threadIdx.x & 63;
    int t = blockIdx.x * 4 + (threadIdx.x >> 6);
    const float* xr = x + (size_t)t * D_DIM;

    float ag[E_NUM] = {}, an[E_NUM] = {};
    for (int it = 0; it < D_DIM / 64; ++it) {
        int d = it * 64 + lane;
        float xv = xr[d];
        float4 g0 = *(const float4*)(Wg + (size_t)d * E_NUM);
        float4 g1 = *(const float4*)(Wg + (size_t)d * E_NUM + 4);
        float4 m0 = *(const float4*)(Wn + (size_t)d * E_NUM);
        float4 m1 = *(const float4*)(Wn + (size_t)d * E_NUM + 4);
        ag[0] += xv * g0.x; ag[1] += xv * g0.y; ag[2] += xv * g0.z; ag[3] += xv * g0.w;
        ag[4] += xv * g1.x; ag[5] += xv * g1.y; ag[6] += xv * g1.z; ag[7] += xv * g1.w;
        an[0] += xv * m0.x; an[1] += xv * m0.y; an[2] += xv * m0.z; an[3] += xv * m0.w;
        an[4] += xv * m1.x; an[5] += xv * m1.y; an[6] += xv * m1.z; an[7] += xv * m1.w;
    }
    #pragma unroll
    for (int off = 32; off > 0; off >>= 1) {
        #pragma unroll
        for (int e = 0; e < E_NUM; ++e) {
            ag[e] += __shfl_xor(ag[e], off);
            an[e] += __shfl_xor(an[e], off);
        }
    }
    if (lane == 0) {
        float nz[E_NUM];
        #pragma unroll
        for (int e = 0; e < E_NUM; ++e) {
            float g = ag[e] + bg[e];
            float nn = an[e] + bn[e];
            float sp = fmaxf(nn, 0.f) + log1pf(expf(-fabsf(nn)));
            float z = g + noise[(size_t)t * E_NUM + e] * sp;
            out_gate[(size_t)t * E_NUM + e] = g;
            out_noisy[(size_t)t * E_NUM + e] = z;
            nz[e] = z;
        }
        int e0 = 0;
        #pragma unroll
        for (int e = 1; e < E_NUM; ++e) if (nz[e] > nz[e0]) e0 = e;
        int e1 = (e0 == 0) ? 1 : 0;
        #pragma unroll
        for (int e = 0; e < E_NUM; ++e) if (e != e0 && nz[e] > nz[e1]) e1 = e;
        float b = expf(nz[e1] - nz[e0]);  // <= 1
        float w0 = 1.f / (1.f + b);
        float w1 = b / (1.f + b);
        tk_idx[t * 2] = e0;  tk_idx[t * 2 + 1] = e1;
        tk_w[t * 2] = w0;    tk_w[t * 2 + 1] = w1;
    }
}

// ---------------- Deterministic group-by-expert (1 block) ----------------
__global__ __launch_bounds__(256) void scan_scatter_kernel(
    const int* __restrict__ tk_idx,
    int* __restrict__ perm, int* __restrict__ meta)
{
    __shared__ int cnt[256][E_NUM];
    __shared__ int soff[E_NUM];
    int tid = threadIdx.x;
    const int PPT = NPAIR / 256;
    int p0 = tid * PPT;

    int c[E_NUM] = {};
    for (int i = 0; i < PPT; ++i) c[tk_idx[p0 + i]]++;
    #pragma unroll
    for (int e = 0; e < E_NUM; ++e) cnt[tid][e] = c[e];
    __syncthreads();

    if (tid < E_NUM) {
        int s = 0;
        for (int j = 0; j < 256; ++j) { int v = cnt[j][tid]; cnt[j][tid] = s; s += v; }
        soff[tid] = s;
    }
    __syncthreads();

    if (tid == 0) {
        int off = 0, nt = 0;
        for (int e = 0; e < E_NUM; ++e) {
            int ce = soff[e];
            meta[1 + e] = off;
            meta[9 + e] = ce;
            for (int j = 0; j < ce; j += BM) {
                meta[32 + nt]  = e;
                meta[160 + nt] = off + j;
                meta[288 + nt] = off + ce;
                nt++;
            }
            off += ce;
        }
        meta[0] = nt;
    }
    __syncthreads();
    if (tid < E_NUM) soff[tid] = meta[1 + tid];
    __syncthreads();

    int pos[E_NUM];
    #pragma unroll
    for (int e = 0; e < E_NUM; ++e) pos[e] = soff[e] + cnt[tid][e];
    for (int i = 0; i < PPT; ++i) {
        int e = tk_idx[p0 + i];
        perm[pos[e]++] = p0 + i;
    }
}

// ---------------- x fp32 -> bf16 ----------------
__global__ __launch_bounds__(256) void convert_x_kernel(
    const float* __restrict__ x, unsigned short* __restrict__ xb)
{
    size_t i = ((size_t)blockIdx.x * 256 + threadIdx.x) * 8;
    float4 a = *(const float4*)(x + i);
    float4 b = *(const float4*)(x + i + 4);
    u16x8 o;
    o[0] = f2bf(a.x); o[1] = f2bf(a.y); o[2] = f2bf(a.z); o[3] = f2bf(a.w);
    o[4] = f2bf(b.x); o[5] = f2bf(b.y); o[6] = f2bf(b.z); o[7] = f2bf(b.w);
    *(u16x8*)(xb + i) = o;
}

// ---------------- W [E][R][C] f32 -> WT [E][C][R] bf16 ----------------
__global__ __launch_bounds__(256) void transpose_kernel(
    const float* __restrict__ W, unsigned short* __restrict__ WT, int R, int C)
{
    __shared__ float tile[32][33];
    int e = blockIdx.z;
    int c0 = blockIdx.x * 32, r0 = blockIdx.y * 32;
    int tx = threadIdx.x & 31, ty = threadIdx.x >> 5;
    const float* src = W + (size_t)e * R * C;
    #pragma unroll
    for (int i = 0; i < 4; ++i)
        tile[ty + 8 * i][tx] = src[(size_t)(r0 + ty + 8 * i) * C + c0 + tx];
    __syncthreads();
    unsigned short* dst = WT + (size_t)e * C * R;
    #pragma unroll
    for (int i = 0; i < 4; ++i)
        dst[(size_t)(c0 + ty + 8 * i) * R + r0 + tx] = f2bf(tile[tx][ty + 8 * i]);
}

// ---------------- FC1: h = gelu(x @ W1 + b1), grouped, 2-phase pipelined ----------------
__global__ __launch_bounds__(256) void fc1_kernel(
    const unsigned short* __restrict__ xb,    // [T][D] bf16
    const unsigned short* __restrict__ W1T,   // [E][F][D] bf16
    const float* __restrict__ b1,             // [E][F]
    const int* __restrict__ perm,
    const int* __restrict__ meta,
    unsigned short* __restrict__ h)           // [NPAIR][F] bf16
{
    // XCD chunk swizzle (bijective: 2272 % 8 == 0): same-tile n-blocks co-XCD
    const int nwg = 71 * (F_DIM / BN);
    const int cpx = nwg >> 3;
    int bid = blockIdx.x;
    int wg = (bid & 7) * cpx + (bid >> 3);
    int tile = wg >> 5;           // / 32 n-blocks
    int n0 = (wg & 31) * BN;
    if (tile >= meta[0]) return;
    int e    = meta[32 + tile];
    int rs   = meta[160 + tile];
    int rend = meta[288 + tile];

    __shared__ __align__(16) unsigned short As[2][BM * BK];
    __shared__ __align__(16) unsigned short Bs[2][BN * BK];

    int tid = threadIdx.x, lane = tid & 63, wv = tid >> 6;
    int wm = (wv >> 1) * 64, wn = (wv & 1) * 64;
    // pre-swizzled global column so linear gload_lds lands data in swizzled slots
    int csw = ((tid & 7) ^ ((tid >> 3) & 7)) * 8;

    const unsigned short* asrc[4];
    #pragma unroll
    for (int i = 0; i < 4; ++i) {
        int q = tid + i * 256;
        int pos = rs + (q >> 3); if (pos >= NPAIR) pos = NPAIR - 1;
        int t = perm[pos] >> 1;
        asrc[i] = xb + (size_t)t * D_DIM + csw;
    }
    const unsigned short* bbase = W1T + ((size_t)e * F_DIM + n0 + wv * 32 + (lane >> 3)) * D_DIM + csw;

    f32x4 acc[4][4] = {};

#define STAGE1(k0, b) do { \
    _Pragma("unroll") \
    for (int i_ = 0; i_ < 4; ++i_) \
        load_lds16(asrc[i_] + (k0), &As[b][(wv * 64 + i_ * 256) * 8]); \
    _Pragma("unroll") \
    for (int j_ = 0; j_ < 4; ++j_) \
        load_lds16(bbase + (size_t)(j_ * 8) * D_DIM + (k0), &Bs[b][(wv * 32 + j_ * 8) * BK]); \
} while (0)

    STAGE1(0, 0);
    const int NT = D_DIM / BK;   // 16
    #pragma unroll 2
    for (int t = 0; t < NT; ++t) {
        int cur = t & 1;
        if (t + 1 < NT) {
            STAGE1((t + 1) * BK, cur ^ 1);
            asm volatile("s_waitcnt vmcnt(8)" ::: "memory");   // cur's loads landed; next's fly
        } else {
            asm volatile("s_waitcnt vmcnt(0)" ::: "memory");
        }
        __builtin_amdgcn_s_barrier();
        const unsigned short* A = As[cur];
        const unsigned short* B = Bs[cur];
        #pragma unroll
        for (int kk = 0; kk < BK; kk += 32) {
            bf16x8 af[4], bf[4];
            #pragma unroll
            for (int m = 0; m < 4; ++m)
                af[m] = lds_frag(A, wm + m * 16 + (lane & 15), kk + (lane >> 4) * 8);
            #pragma unroll
            for (int n = 0; n < 4; ++n)
                bf[n] = lds_frag(B, wn + n * 16 + (lane & 15), kk + (lane >> 4) * 8);
            #pragma unroll
            for (int m = 0; m < 4; ++m)
                #pragma unroll
                for (int n = 0; n < 4; ++n)
                    acc[m][n] = __builtin_amdgcn_mfma_f32_16x16x32_bf16(af[m], bf[n], acc[m][n], 0, 0, 0);
        }
        asm volatile("s_waitcnt lgkmcnt(0)" ::: "memory");
        __builtin_amdgcn_s_barrier();   // all waves done reading buf[cur] before overwrite
    }
#undef STAGE1

    #pragma unroll
    for (int m = 0; m < 4; ++m) {
        #pragma unroll
        for (int j = 0; j < 4; ++j) {
            int r = wm + m * 16 + (lane >> 4) * 4 + j;
            int pos = rs + r;
            if (pos >= rend) continue;
            #pragma unroll
            for (int n = 0; n < 4; ++n) {
                int col = n0 + wn + n * 16 + (lane & 15);
                float v = acc[m][n][j] + b1[e * F_DIM + col];
                v = 0.5f * v * (1.f + erff(v * 0.70710678118654752f));  // exact GELU
                h[(size_t)pos * F_DIM + col] = f2bf(v);
            }
        }
    }
}

// ---------------- FC2: out += w * (h @ W2 + b2), grouped, 2-phase pipelined ----------------
__global__ __launch_bounds__(256) void fc2_kernel(
    const unsigned short* __restrict__ h,     // [NPAIR][F] bf16 (grouped rows: contiguous!)
    const unsigned short* __restrict__ W2T,   // [E][D][F] bf16
    const float* __restrict__ b2,             // [E][D]
    const int* __restrict__ perm,
    const float* __restrict__ tk_w,
    const int* __restrict__ meta,
    float* __restrict__ out)                  // [T][D] fp32 (zeroed)
{
    const int nwg = 71 * (D_DIM / BN);        // 568, % 8 == 0
    const int cpx = nwg >> 3;
    int bid = blockIdx.x;
    int wg = (bid & 7) * cpx + (bid >> 3);
    int tile = wg >> 3;           // / 8 n-blocks
    int n0 = (wg & 7) * BN;
    if (tile >= meta[0]) return;
    int e    = meta[32 + tile];
    int rs   = meta[160 + tile];
    int rend = meta[288 + tile];

    __shared__ __align__(16) unsigned short As[2][BM * BK];
    __shared__ __align__(16) unsigned short Bs[2][BN * BK];

    int tid = threadIdx.x, lane = tid & 63, wv = tid >> 6;
    int wm = (wv >> 1) * 64, wn = (wv & 1) * 64;
    int csw = ((tid & 7) ^ ((tid >> 3) & 7)) * 8;

    const unsigned short* asrc[4];
    #pragma unroll
    for (int i = 0; i < 4; ++i) {
        int q = tid + i * 256;
        int pos = rs + (q >> 3); if (pos >= NPAIR) pos = NPAIR - 1;
        asrc[i] = h + (size_t)pos * F_DIM + csw;
    }
    const unsigned short* bbase = W2T + ((size_t)e * D_DIM + n0 + wv * 32 + (lane >> 3)) * F_DIM + csw;

    f32x4 acc[4][4] = {};

#define STAGE2(k0, b) do { \
    _Pragma("unroll") \
    for (int i_ = 0; i_ < 4; ++i_) \
        load_lds16(asrc[i_] + (k0), &As[b][(wv * 64 + i_ * 256) * 8]); \
    _Pragma("unroll") \
    for (int j_ = 0; j_ < 4; ++j_) \
        load_lds16(bbase + (size_t)(j_ * 8) * F_DIM + (k0), &Bs[b][(wv * 32 + j_ * 8) * BK]); \
} while (0)

    STAGE2(0, 0);
    const int NT = F_DIM / BK;   // 64
    #pragma unroll 2
    for (int t = 0; t < NT; ++t) {
        int cur = t & 1;
        if (t + 1 < NT) {
            STAGE2((t + 1) * BK, cur ^ 1);
            asm volatile("s_waitcnt vmcnt(8)" ::: "memory");
        } else {
            asm volatile("s_waitcnt vmcnt(0)" ::: "memory");
        }
        __builtin_amdgcn_s_barrier();
        const unsigned short* A = As[cur];
        const unsigned short* B = Bs[cur];
        #pragma unroll
        for (int kk = 0; kk < BK; kk += 32) {
            bf16x8 af[4], bf[4];
            #pragma unroll
            for (int m = 0; m < 4; ++m)
                af[m] = lds_frag(A, wm + m * 16 + (lane & 15), kk + (lane >> 4) * 8);
            #pragma unroll
            for (int n = 0; n < 4; ++n)
                bf[n] = lds_frag(B, wn + n * 16 + (lane & 15), kk + (lane >> 4) * 8);
            #pragma unroll
            for (int m = 0; m < 4; ++m)
                #pragma unroll
                for (int n = 0; n < 4; ++n)
                    acc[m][n] = __builtin_amdgcn_mfma_f32_16x16x32_bf16(af[m], bf[n], acc[m][n], 0, 0, 0);
        }
        asm volatile("s_waitcnt lgkmcnt(0)" ::: "memory");
        __builtin_amdgcn_s_barrier();
    }
#undef STAGE2

    #pragma unroll
    for (int m = 0; m < 4; ++m) {
        #pragma unroll
        for (int j = 0; j < 4; ++j) {
            int r = wm + m * 16 + (lane >> 4) * 4 + j;
            int pos = rs + r;
            if (pos >= rend) continue;
            int pr = perm[pos];
            int t = pr >> 1;
            float w = tk_w[pr];
            #pragma unroll
            for (int n = 0; n < 4; ++n) {
                int col = n0 + wn + n * 16 + (lane & 15);
                float v = (acc[m][n][j] + b2[e * D_DIM + col]) * w;
                atomicAdd(&out[(size_t)t * D_DIM + col], v);
            }
        }
    }
}

extern "C" void kernel_launch(void* const* d_in, const int* in_sizes, int n_in,
                              void* d_out, int out_size, void* d_ws, size_t ws_size,
                              hipStream_t stream)
{
    const float* x     = (const float*)d_in[0];
    const float* noise = (const float*)d_in[1];
    const float* Wg    = (const float*)d_in[2];
    const float* bg    = (const float*)d_in[3];
    const float* Wn    = (const float*)d_in[4];
    const float* bn    = (const float*)d_in[5];
    const float* W1    = (const float*)d_in[6];
    const float* b1    = (const float*)d_in[7];
    const float* W2    = (const float*)d_in[8];
    const float* b2    = (const float*)d_in[9];

    float* out       = (float*)d_out;
    float* out_noisy = out + (size_t)T_TOK * D_DIM;
    float* out_gate  = out_noisy + (size_t)T_TOK * E_NUM;

    char* ws = (char*)d_ws;
    int*   tk_idx = (int*)ws;
    float* tk_w   = (float*)(ws + 32768);
    int*   perm   = (int*)(ws + 65536);
    int*   meta   = (int*)(ws + 98304);
    size_t off = 131072;
    unsigned short* xb   = (unsigned short*)(ws + off); off += (size_t)T_TOK * D_DIM * 2;
    unsigned short* W1T  = (unsigned short*)(ws + off); off += (size_t)E_NUM * F_DIM * D_DIM * 2;
    unsigned short* W2T  = (unsigned short*)(ws + off); off += (size_t)E_NUM * D_DIM * F_DIM * 2;
    unsigned short* hbuf = (unsigned short*)(ws + off); off += (size_t)NPAIR * F_DIM * 2;

    hipMemsetAsync(d_out, 0, (size_t)out_size * sizeof(float), stream);

    router_kernel<<<T_TOK / 4, 256, 0, stream>>>(x, noise, Wg, bg, Wn, bn,
                                                 out_noisy, out_gate, tk_idx, tk_w);
    scan_scatter_kernel<<<1, 256, 0, stream>>>(tk_idx, perm, meta);
    convert_x_kernel<<<(T_TOK * D_DIM) / (256 * 8), 256, 0, stream>>>(x, xb);
    transpose_kernel<<<dim3(F_DIM / 32, D_DIM / 32, E_NUM), 256, 0, stream>>>(W1, W1T, D_DIM, F_DIM);
    transpose_kernel<<<dim3(D_DIM / 32, F_DIM / 32, E_NUM), 256, 0, stream>>>(W2, W2T, F_DIM, D_DIM);

    fc1_kernel<<<71 * (F_DIM / BN), 256, 0, stream>>>(xb, W1T, b1, perm, meta, hbuf);
    fc2_kernel<<<71 * (D_DIM / BN), 256, 0, stream>>>(hbuf, W2T, b2, perm, tk_w, meta, out);
}

// Round 4
// 478.273 us; speedup vs baseline: 1.3267x; 1.0578x over previous
//
#include <hip/hip_runtime.h>
#include <hip/hip_bf16.h>

#define T_TOK 4096
#define D_DIM 1024
#define E_NUM 8
#define F_DIM 4096
#define NPAIR 8192

#define BM 128
#define BN 128
#define BK 64

typedef float f32x4 __attribute__((ext_vector_type(4)));
typedef __bf16 bf16x8 __attribute__((ext_vector_type(8)));
typedef unsigned short u16x8 __attribute__((ext_vector_type(8)));

__device__ __forceinline__ unsigned short f2bf(float f) {
    unsigned int u = __float_as_uint(f);
    u += 0x7fffu + ((u >> 16) & 1u);
    return (unsigned short)(u >> 16);
}

typedef const __attribute__((address_space(1))) void GV;
typedef __attribute__((address_space(3))) void LV;

__device__ __forceinline__ void load_lds16(const void* g, void* l) {
    __builtin_amdgcn_global_load_lds((GV*)g, (LV*)l, 16, 0, 0);
}

// Swizzled LDS fragment read: logical (row, colShort cs) lives at
// byte = row*128 + ((cs*2) ^ ((row&7)<<4)). Writer: gload_lds writes linearly;
// the per-lane GLOBAL source column carries the matching permutation.
__device__ __forceinline__ bf16x8 lds_frag(const unsigned short* S, int row, int cs) {
    int byte = row * (BK * 2) + ((cs * 2) ^ ((row & 7) << 4));
    return *(const bf16x8*)((const char*)S + byte);
}

// ---------------- Router: one wave per token ----------------
__global__ __launch_bounds__(256) void router_kernel(
    const float* __restrict__ x, const float* __restrict__ noise,
    const float* __restrict__ Wg, const float* __restrict__ bg,
    const float* __restrict__ Wn, const float* __restrict__ bn,
    float* __restrict__ out_noisy, float* __restrict__ out_gate,
    int* __restrict__ tk_idx, float* __restrict__ tk_w)
{
    int lane = threadIdx.x & 63;
    int t = blockIdx.x * 4 + (threadIdx.x >> 6);
    const float* xr = x + (size_t)t * D_DIM;

    float ag[E_NUM] = {}, an[E_NUM] = {};
    for (int it = 0; it < D_DIM / 64; ++it) {
        int d = it * 64 + lane;
        float xv = xr[d];
        float4 g0 = *(const float4*)(Wg + (size_t)d * E_NUM);
        float4 g1 = *(const float4*)(Wg + (size_t)d * E_NUM + 4);
        float4 m0 = *(const float4*)(Wn + (size_t)d * E_NUM);
        float4 m1 = *(const float4*)(Wn + (size_t)d * E_NUM + 4);
        ag[0] += xv * g0.x; ag[1] += xv * g0.y; ag[2] += xv * g0.z; ag[3] += xv * g0.w;
        ag[4] += xv * g1.x; ag[5] += xv * g1.y; ag[6] += xv * g1.z; ag[7] += xv * g1.w;
        an[0] += xv * m0.x; an[1] += xv * m0.y; an[2] += xv * m0.z; an[3] += xv * m0.w;
        an[4] += xv * m1.x; an[5] += xv * m1.y; an[6] += xv * m1.z; an[7] += xv * m1.w;
    }
    #pragma unroll
    for (int off = 32; off > 0; off >>= 1) {
        #pragma unroll
        for (int e = 0; e < E_NUM; ++e) {
            ag[e] += __shfl_xor(ag[e], off);
            an[e] += __shfl_xor(an[e], off);
        }
    }
    if (lane == 0) {
        float nz[E_NUM];
        #pragma unroll
        for (int e = 0; e < E_NUM; ++e) {
            float g = ag[e] + bg[e];
            float nn = an[e] + bn[e];
            float sp = fmaxf(nn, 0.f) + log1pf(expf(-fabsf(nn)));
            float z = g + noise[(size_t)t * E_NUM + e] * sp;
            out_gate[(size_t)t * E_NUM + e] = g;
            out_noisy[(size_t)t * E_NUM + e] = z;
            nz[e] = z;
        }
        int e0 = 0;
        #pragma unroll
        for (int e = 1; e < E_NUM; ++e) if (nz[e] > nz[e0]) e0 = e;
        int e1 = (e0 == 0) ? 1 : 0;
        #pragma unroll
        for (int e = 0; e < E_NUM; ++e) if (e != e0 && nz[e] > nz[e1]) e1 = e;
        float b = expf(nz[e1] - nz[e0]);  // <= 1
        float w0 = 1.f / (1.f + b);
        float w1 = b / (1.f + b);
        tk_idx[t * 2] = e0;  tk_idx[t * 2 + 1] = e1;
        tk_w[t * 2] = w0;    tk_w[t * 2 + 1] = w1;
    }
}

// ---------------- Deterministic group-by-expert (1 block) ----------------
__global__ __launch_bounds__(256) void scan_scatter_kernel(
    const int* __restrict__ tk_idx,
    int* __restrict__ perm, int* __restrict__ meta)
{
    __shared__ int cnt[256][E_NUM];
    __shared__ int soff[E_NUM];
    int tid = threadIdx.x;
    const int PPT = NPAIR / 256;
    int p0 = tid * PPT;

    int c[E_NUM] = {};
    for (int i = 0; i < PPT; ++i) c[tk_idx[p0 + i]]++;
    #pragma unroll
    for (int e = 0; e < E_NUM; ++e) cnt[tid][e] = c[e];
    __syncthreads();

    if (tid < E_NUM) {
        int s = 0;
        for (int j = 0; j < 256; ++j) { int v = cnt[j][tid]; cnt[j][tid] = s; s += v; }
        soff[tid] = s;
    }
    __syncthreads();

    if (tid == 0) {
        int off = 0, nt = 0;
        for (int e = 0; e < E_NUM; ++e) {
            int ce = soff[e];
            meta[1 + e] = off;
            meta[9 + e] = ce;
            for (int j = 0; j < ce; j += BM) {
                meta[32 + nt]  = e;
                meta[160 + nt] = off + j;
                meta[288 + nt] = off + ce;
                nt++;
            }
            off += ce;
        }
        meta[0] = nt;
    }
    __syncthreads();
    if (tid < E_NUM) soff[tid] = meta[1 + tid];
    __syncthreads();

    int pos[E_NUM];
    #pragma unroll
    for (int e = 0; e < E_NUM; ++e) pos[e] = soff[e] + cnt[tid][e];
    for (int i = 0; i < PPT; ++i) {
        int e = tk_idx[p0 + i];
        perm[pos[e]++] = p0 + i;
    }
}

// ---------------- x fp32 -> bf16 ----------------
__global__ __launch_bounds__(256) void convert_x_kernel(
    const float* __restrict__ x, unsigned short* __restrict__ xb)
{
    size_t i = ((size_t)blockIdx.x * 256 + threadIdx.x) * 8;
    float4 a = *(const float4*)(x + i);
    float4 b = *(const float4*)(x + i + 4);
    u16x8 o;
    o[0] = f2bf(a.x); o[1] = f2bf(a.y); o[2] = f2bf(a.z); o[3] = f2bf(a.w);
    o[4] = f2bf(b.x); o[5] = f2bf(b.y); o[6] = f2bf(b.z); o[7] = f2bf(b.w);
    *(u16x8*)(xb + i) = o;
}

// ---------------- W [E][R][C] f32 -> WT [E][C][R] bf16 ----------------
__global__ __launch_bounds__(256) void transpose_kernel(
    const float* __restrict__ W, unsigned short* __restrict__ WT, int R, int C)
{
    __shared__ float tile[32][33];
    int e = blockIdx.z;
    int c0 = blockIdx.x * 32, r0 = blockIdx.y * 32;
    int tx = threadIdx.x & 31, ty = threadIdx.x >> 5;
    const float* src = W + (size_t)e * R * C;
    #pragma unroll
    for (int i = 0; i < 4; ++i)
        tile[ty + 8 * i][tx] = src[(size_t)(r0 + ty + 8 * i) * C + c0 + tx];
    __syncthreads();
    unsigned short* dst = WT + (size_t)e * C * R;
    #pragma unroll
    for (int i = 0; i < 4; ++i)
        dst[(size_t)(c0 + ty + 8 * i) * R + r0 + tx] = f2bf(tile[tx][ty + 8 * i]);
}

// ---------------- FC1: h = gelu(x @ W1 + b1), grouped, single-buffer m97-style ----------------
__global__ __launch_bounds__(256, 4) void fc1_kernel(
    const unsigned short* __restrict__ xb,    // [T][D] bf16
    const unsigned short* __restrict__ W1T,   // [E][F][D] bf16
    const float* __restrict__ b1,             // [E][F]
    const int* __restrict__ perm,
    const int* __restrict__ meta,
    unsigned short* __restrict__ h)           // [NPAIR][F] bf16
{
    // XCD chunk swizzle (bijective: 2272 % 8 == 0): same-tile n-blocks co-XCD
    const int nwg = 71 * (F_DIM / BN);
    const int cpx = nwg >> 3;
    int bid = blockIdx.x;
    int wg = (bid & 7) * cpx + (bid >> 3);
    int tile = wg >> 5;           // / 32 n-blocks
    int n0 = (wg & 31) * BN;
    if (tile >= meta[0]) return;
    int e    = meta[32 + tile];
    int rs   = meta[160 + tile];
    int rend = meta[288 + tile];

    __shared__ __align__(16) unsigned short As[BM * BK];   // 16 KB
    __shared__ __align__(16) unsigned short Bs[BN * BK];   // 16 KB

    int tid = threadIdx.x, lane = tid & 63, wv = tid >> 6;
    int wm = (wv >> 1) * 64, wn = (wv & 1) * 64;
    // pre-swizzled global column so linear gload_lds lands data in swizzled slots
    int csw = ((tid & 7) ^ ((tid >> 3) & 7)) * 8;

    const unsigned short* asrc[4];
    #pragma unroll
    for (int i = 0; i < 4; ++i) {
        int q = tid + i * 256;
        int pos = rs + (q >> 3); if (pos >= NPAIR) pos = NPAIR - 1;
        int t = perm[pos] >> 1;
        asrc[i] = xb + (size_t)t * D_DIM + csw;
    }
    const unsigned short* bbase = W1T + ((size_t)e * F_DIM + n0 + wv * 32 + (lane >> 3)) * D_DIM + csw;

    f32x4 acc[4][4] = {};

    const int NT = D_DIM / BK;   // 16
    for (int t = 0; t < NT; ++t) {
        int k0 = t * BK;
        #pragma unroll
        for (int i = 0; i < 4; ++i)
            load_lds16(asrc[i] + k0, &As[(wv * 64 + i * 256) * 8]);
        #pragma unroll
        for (int j = 0; j < 4; ++j)
            load_lds16(bbase + (size_t)(j * 8) * D_DIM + k0, &Bs[(wv * 32 + j * 8) * BK]);
        asm volatile("s_waitcnt vmcnt(0)" ::: "memory");
        __builtin_amdgcn_s_barrier();
        #pragma unroll
        for (int kk = 0; kk < BK; kk += 32) {
            bf16x8 af[4], bf[4];
            #pragma unroll
            for (int m = 0; m < 4; ++m)
                af[m] = lds_frag(As, wm + m * 16 + (lane & 15), kk + (lane >> 4) * 8);
            #pragma unroll
            for (int n = 0; n < 4; ++n)
                bf[n] = lds_frag(Bs, wn + n * 16 + (lane & 15), kk + (lane >> 4) * 8);
            #pragma unroll
            for (int m = 0; m < 4; ++m)
                #pragma unroll
                for (int n = 0; n < 4; ++n)
                    acc[m][n] = __builtin_amdgcn_mfma_f32_16x16x32_bf16(af[m], bf[n], acc[m][n], 0, 0, 0);
        }
        asm volatile("s_waitcnt lgkmcnt(0)" ::: "memory");
        __builtin_amdgcn_s_barrier();   // all waves done reading before next STAGE overwrites
    }

    #pragma unroll
    for (int m = 0; m < 4; ++m) {
        #pragma unroll
        for (int j = 0; j < 4; ++j) {
            int r = wm + m * 16 + (lane >> 4) * 4 + j;
            int pos = rs + r;
            if (pos >= rend) continue;
            #pragma unroll
            for (int n = 0; n < 4; ++n) {
                int col = n0 + wn + n * 16 + (lane & 15);
                float v = acc[m][n][j] + b1[e * F_DIM + col];
                v = 0.5f * v * (1.f + erff(v * 0.70710678118654752f));  // exact GELU
                h[(size_t)pos * F_DIM + col] = f2bf(v);
            }
        }
    }
}

// ---------------- FC2: out += w * (h @ W2 + b2), grouped, split-K=2, single-buffer ----------------
__global__ __launch_bounds__(256, 4) void fc2_kernel(
    const unsigned short* __restrict__ h,     // [NPAIR][F] bf16 (grouped rows: contiguous)
    const unsigned short* __restrict__ W2T,   // [E][D][F] bf16
    const float* __restrict__ b2,             // [E][D]
    const int* __restrict__ perm,
    const float* __restrict__ tk_w,
    const int* __restrict__ meta,
    float* __restrict__ out)                  // [T][D] fp32 (zeroed)
{
    const int nwg = 71 * (D_DIM / BN) * 2;    // 1136, % 8 == 0
    const int cpx = nwg >> 3;
    int bid = blockIdx.x;
    int wg = (bid & 7) * cpx + (bid >> 3);
    int tile = wg >> 4;           // / (8 n-blocks * 2 ksplit)
    int rem  = wg & 15;
    int n0 = (rem >> 1) * BN;
    int ks = rem & 1;
    if (tile >= meta[0]) return;
    int e    = meta[32 + tile];
    int rs   = meta[160 + tile];
    int rend = meta[288 + tile];
    int kbeg = ks * (F_DIM / 2);

    __shared__ __align__(16) unsigned short As[BM * BK];
    __shared__ __align__(16) unsigned short Bs[BN * BK];

    int tid = threadIdx.x, lane = tid & 63, wv = tid >> 6;
    int wm = (wv >> 1) * 64, wn = (wv & 1) * 64;
    int csw = ((tid & 7) ^ ((tid >> 3) & 7)) * 8;

    const unsigned short* asrc[4];
    #pragma unroll
    for (int i = 0; i < 4; ++i) {
        int q = tid + i * 256;
        int pos = rs + (q >> 3); if (pos >= NPAIR) pos = NPAIR - 1;
        asrc[i] = h + (size_t)pos * F_DIM + kbeg + csw;
    }
    const unsigned short* bbase = W2T + ((size_t)e * D_DIM + n0 + wv * 32 + (lane >> 3)) * F_DIM
                                + kbeg + csw;

    f32x4 acc[4][4] = {};

    const int NT = (F_DIM / 2) / BK;   // 32
    for (int t = 0; t < NT; ++t) {
        int k0 = t * BK;
        #pragma unroll
        for (int i = 0; i < 4; ++i)
            load_lds16(asrc[i] + k0, &As[(wv * 64 + i * 256) * 8]);
        #pragma unroll
        for (int j = 0; j < 4; ++j)
            load_lds16(bbase + (size_t)(j * 8) * F_DIM + k0, &Bs[(wv * 32 + j * 8) * BK]);
        asm volatile("s_waitcnt vmcnt(0)" ::: "memory");
        __builtin_amdgcn_s_barrier();
        #pragma unroll
        for (int kk = 0; kk < BK; kk += 32) {
            bf16x8 af[4], bf[4];
            #pragma unroll
            for (int m = 0; m < 4; ++m)
                af[m] = lds_frag(As, wm + m * 16 + (lane & 15), kk + (lane >> 4) * 8);
            #pragma unroll
            for (int n = 0; n < 4; ++n)
                bf[n] = lds_frag(Bs, wn + n * 16 + (lane & 15), kk + (lane >> 4) * 8);
            #pragma unroll
            for (int m = 0; m < 4; ++m)
                #pragma unroll
                for (int n = 0; n < 4; ++n)
                    acc[m][n] = __builtin_amdgcn_mfma_f32_16x16x32_bf16(af[m], bf[n], acc[m][n], 0, 0, 0);
        }
        asm volatile("s_waitcnt lgkmcnt(0)" ::: "memory");
        __builtin_amdgcn_s_barrier();
    }

    #pragma unroll
    for (int m = 0; m < 4; ++m) {
        #pragma unroll
        for (int j = 0; j < 4; ++j) {
            int r = wm + m * 16 + (lane >> 4) * 4 + j;
            int pos = rs + r;
            if (pos >= rend) continue;
            int pr = perm[pos];
            int t = pr >> 1;
            float w = tk_w[pr];
            #pragma unroll
            for (int n = 0; n < 4; ++n) {
                int col = n0 + wn + n * 16 + (lane & 15);
                float base = (ks == 0) ? b2[e * D_DIM + col] : 0.f;
                float v = (acc[m][n][j] + base) * w;
                atomicAdd(&out[(size_t)t * D_DIM + col], v);
            }
        }
    }
}

extern "C" void kernel_launch(void* const* d_in, const int* in_sizes, int n_in,
                              void* d_out, int out_size, void* d_ws, size_t ws_size,
                              hipStream_t stream)
{
    const float* x     = (const float*)d_in[0];
    const float* noise = (const float*)d_in[1];
    const float* Wg    = (const float*)d_in[2];
    const float* bg    = (const float*)d_in[3];
    const float* Wn    = (const float*)d_in[4];
    const float* bn    = (const float*)d_in[5];
    const float* W1    = (const float*)d_in[6];
    const float* b1    = (const float*)d_in[7];
    const float* W2    = (const float*)d_in[8];
    const float* b2    = (const float*)d_in[9];

    float* out       = (float*)d_out;
    float* out_noisy = out + (size_t)T_TOK * D_DIM;
    float* out_gate  = out_noisy + (size_t)T_TOK * E_NUM;

    char* ws = (char*)d_ws;
    int*   tk_idx = (int*)ws;
    float* tk_w   = (float*)(ws + 32768);
    int*   perm   = (int*)(ws + 65536);
    int*   meta   = (int*)(ws + 98304);
    size_t off = 131072;
    unsigned short* xb   = (unsigned short*)(ws + off); off += (size_t)T_TOK * D_DIM * 2;
    unsigned short* W1T  = (unsigned short*)(ws + off); off += (size_t)E_NUM * F_DIM * D_DIM * 2;
    unsigned short* W2T  = (unsigned short*)(ws + off); off += (size_t)E_NUM * D_DIM * F_DIM * 2;
    unsigned short* hbuf = (unsigned short*)(ws + off); off += (size_t)NPAIR * F_DIM * 2;

    hipMemsetAsync(d_out, 0, (size_t)out_size * sizeof(float), stream);

    router_kernel<<<T_TOK / 4, 256, 0, stream>>>(x, noise, Wg, bg, Wn, bn,
                                                 out_noisy, out_gate, tk_idx, tk_w);
    scan_scatter_kernel<<<1, 256, 0, stream>>>(tk_idx, perm, meta);
    convert_x_kernel<<<(T_TOK * D_DIM) / (256 * 8), 256, 0, stream>>>(x, xb);
    transpose_kernel<<<dim3(F_DIM / 32, D_DIM / 32, E_NUM), 256, 0, stream>>>(W1, W1T, D_DIM, F_DIM);
    transpose_kernel<<<dim3(D_DIM / 32, F_DIM / 32, E_NUM), 256, 0, stream>>>(W2, W2T, F_DIM, D_DIM);

    fc1_kernel<<<71 * (F_DIM / BN), 256, 0, stream>>>(xb, W1T, b1, perm, meta, hbuf);
    fc2_kernel<<<71 * (D_DIM / BN) * 2, 256, 0, stream>>>(hbuf, W2T, b2, perm, tk_w, meta, out);
}